// Round 1
// baseline (126.571 us; speedup 1.0000x reference)
//
#include <hip/hip_runtime.h>
#include <hip/hip_bf16.h>
#include <stdint.h>

#define BATCH 8192
#define IN    1024
#define OUTD  1024
#define PBASIS 8

typedef __attribute__((ext_vector_type(8))) short bf16x8;
typedef __attribute__((ext_vector_type(4))) float floatx4;

__device__ __forceinline__ unsigned short f2bf(float f) {
    union { float f; unsigned u; } v; v.f = f;
    unsigned u = v.u;
    u += 0x7fffu + ((u >> 16) & 1u);   // RNE; inputs finite randn
    return (unsigned short)(u >> 16);
}

// Fused prep: blocks [0,4096) convert x -> bf16 (8 elem/thread);
// blocks [4096,6144) compute w_eff = bf16(sum_p coef * w) (2 elem/thread).
__global__ void prep_kernel(const float* __restrict__ x,
                            const float* __restrict__ coef,
                            const float* __restrict__ w,
                            unsigned short* __restrict__ xb,
                            unsigned short* __restrict__ weff) {
    int b = blockIdx.x;
    int tid = threadIdx.x;
    if (b < 4096) {
        int idx = b * 256 + tid;
        const float4* p = (const float4*)(x + (size_t)idx * 8);
        float4 a = p[0], c = p[1];
        uint4 o;
        o.x = (unsigned)f2bf(a.x) | ((unsigned)f2bf(a.y) << 16);
        o.y = (unsigned)f2bf(a.z) | ((unsigned)f2bf(a.w) << 16);
        o.z = (unsigned)f2bf(c.x) | ((unsigned)f2bf(c.y) << 16);
        o.w = (unsigned)f2bf(c.z) | ((unsigned)f2bf(c.w) << 16);
        ((uint4*)xb)[idx] = o;
    } else {
        int idx = (b - 4096) * 256 + tid;   // element pair index
        size_t e0 = (size_t)idx * 2;
        const float4* c4 = (const float4*)(coef + e0 * PBASIS);
        float4 a = c4[0], bb = c4[1], c = c4[2], d = c4[3];
        float s0 = (a.x + a.y + a.z + a.w) + (bb.x + bb.y + bb.z + bb.w);
        float s1 = (c.x + c.y + c.z + c.w) + (d.x + d.y + d.z + d.w);
        float2 ww = ((const float2*)w)[idx];
        unsigned b0 = f2bf(s0 * ww.x);
        unsigned b1 = f2bf(s1 * ww.y);
        ((unsigned*)weff)[idx] = b0 | (b1 << 16);
    }
}

// Direct global->LDS staging (no VGPR round trip, no ds_write).
// LDS dest must be linear in thread order (wave-uniform base + lane*16);
// the XOR swizzle is applied by PRE-SWIZZLING the global source column
// (involution), so LDS contents are bit-identical to the reg-staged R6
// kernel and the fragment-read side / epilogue are unchanged.
__device__ __forceinline__ void gload_lds16(const void* g, void* l) {
    __builtin_amdgcn_global_load_lds(
        (const __attribute__((address_space(1))) unsigned int*)g,
        (__attribute__((address_space(3))) unsigned int*)l,
        16, 0, 0);
}

// C[m,n] = sum_k A[m,k]*B[n,k]; A=[8192,1024], B=[1024,1024] bf16, C f32.
// 128x128 tile, BK=64, 4 waves (2x2), wave 4x4 of 16x16x32 MFMA.
// m97 structure: per K-step { 8x global_load_lds_dwordx4 -> barrier
// (vmcnt drain) -> 16 ds_read_b128 + 32 MFMA -> barrier }. Grid 512 =
// exactly 2 blocks/CU; cross-block wave overlap hides the drain.
__global__ __launch_bounds__(256, 2) void gemm_bt(
        const unsigned short* __restrict__ A,
        const unsigned short* __restrict__ B,
        float* __restrict__ C) {
    constexpr int K = IN, BK = 64;
    constexpr int ES = 132;                        // epilogue row stride (floats)
    __shared__ __align__(16) char smem[32768];     // A 16K + B 16K; ebuf 32*132*4
    unsigned short* As = (unsigned short*)smem;    // 128 x 64 bf16
    unsigned short* Bs = As + 128 * BK;            // 128 x 64 bf16
    float* ebuf = (float*)smem;                    // epilogue reuse

    const int tid  = threadIdx.x;
    const int bm   = blockIdx.x, bn = blockIdx.y;
    const int lane = tid & 63;
    const int wave = tid >> 6;
    const int wm   = wave & 1, wn = wave >> 1;
    const int t    = lane & 15;    // M/N index within 16
    const int q    = lane >> 4;    // K-quad
    const int r8   = t & 7;        // XOR swizzle key

    // ---- staging addresses ----
    // chunk g = j*256 + tid; row = g>>3; c = g&7.
    // LDS slot = g (LINEAR, required by global_load_lds);
    // global source column = c ^ (row&7)  (pre-swizzled; involution).
    int g0 = tid,       r0 = g0 >> 3, cs0 = (g0 & 7) ^ (r0 & 7);
    int g1 = 256 + tid, r1 = g1 >> 3, cs1 = (g1 & 7) ^ (r1 & 7);
    int g2 = 512 + tid, r2 = g2 >> 3, cs2 = (g2 & 7) ^ (r2 & 7);
    int g3 = 768 + tid, r3 = g3 >> 3, cs3 = (g3 & 7) ^ (r3 & 7);

    const unsigned short* gA0 = A + (size_t)(bm * 128 + r0) * K + cs0 * 8;
    const unsigned short* gA1 = A + (size_t)(bm * 128 + r1) * K + cs1 * 8;
    const unsigned short* gA2 = A + (size_t)(bm * 128 + r2) * K + cs2 * 8;
    const unsigned short* gA3 = A + (size_t)(bm * 128 + r3) * K + cs3 * 8;
    const unsigned short* gB0 = B + (size_t)(bn * 128 + r0) * K + cs0 * 8;
    const unsigned short* gB1 = B + (size_t)(bn * 128 + r1) * K + cs1 * 8;
    const unsigned short* gB2 = B + (size_t)(bn * 128 + r2) * K + cs2 * 8;
    const unsigned short* gB3 = B + (size_t)(bn * 128 + r3) * K + cs3 * 8;

    unsigned short* dA0 = As + g0 * 8;  unsigned short* dB0 = Bs + g0 * 8;
    unsigned short* dA1 = As + g1 * 8;  unsigned short* dB1 = Bs + g1 * 8;
    unsigned short* dA2 = As + g2 * 8;  unsigned short* dB2 = Bs + g2 * 8;
    unsigned short* dA3 = As + g3 * 8;  unsigned short* dB3 = Bs + g3 * 8;

    // ---- fragment base pointers (verified): phys chunk (kh*4+q)^r8 ----
    const unsigned short* aB0 = As + (wm * 64 + t) * BK + ((0 + q) ^ r8) * 8;
    const unsigned short* aB1 = As + (wm * 64 + t) * BK + ((4 + q) ^ r8) * 8;
    const unsigned short* bB0 = Bs + (wn * 64 + t) * BK + ((0 + q) ^ r8) * 8;
    const unsigned short* bB1 = Bs + (wn * 64 + t) * BK + ((4 + q) ^ r8) * 8;

    floatx4 acc[4][4];
#pragma unroll
    for (int i = 0; i < 4; ++i)
#pragma unroll
        for (int j = 0; j < 4; ++j)
            acc[i][j] = (floatx4){0.f, 0.f, 0.f, 0.f};

#define COMPUTE()                                                   \
    {                                                               \
        bf16x8 af0, af1, af2, af3, ag0, ag1, ag2, ag3;              \
        bf16x8 bf0, bf1, bf2, bf3, bg0, bg1, bg2, bg3;              \
        af0 = *(const bf16x8*)(aB0 + 0 * 1024);                     \
        af1 = *(const bf16x8*)(aB0 + 1 * 1024);                     \
        af2 = *(const bf16x8*)(aB0 + 2 * 1024);                     \
        af3 = *(const bf16x8*)(aB0 + 3 * 1024);                     \
        ag0 = *(const bf16x8*)(aB1 + 0 * 1024);                     \
        ag1 = *(const bf16x8*)(aB1 + 1 * 1024);                     \
        ag2 = *(const bf16x8*)(aB1 + 2 * 1024);                     \
        ag3 = *(const bf16x8*)(aB1 + 3 * 1024);                     \
        bf0 = *(const bf16x8*)(bB0 + 0 * 1024);                     \
        bf1 = *(const bf16x8*)(bB0 + 1 * 1024);                     \
        bf2 = *(const bf16x8*)(bB0 + 2 * 1024);                     \
        bf3 = *(const bf16x8*)(bB0 + 3 * 1024);                     \
        bg0 = *(const bf16x8*)(bB1 + 0 * 1024);                     \
        bg1 = *(const bf16x8*)(bB1 + 1 * 1024);                     \
        bg2 = *(const bf16x8*)(bB1 + 2 * 1024);                     \
        bg3 = *(const bf16x8*)(bB1 + 3 * 1024);                     \
        bf16x8 afv[4] = {af0, af1, af2, af3};                       \
        bf16x8 agv[4] = {ag0, ag1, ag2, ag3};                       \
        bf16x8 bfv[4] = {bf0, bf1, bf2, bf3};                       \
        bf16x8 bgv[4] = {bg0, bg1, bg2, bg3};                       \
        _Pragma("unroll")                                           \
        for (int i = 0; i < 4; ++i)                                 \
            _Pragma("unroll")                                       \
            for (int j = 0; j < 4; ++j) {                           \
                acc[i][j] = __builtin_amdgcn_mfma_f32_16x16x32_bf16(\
                    afv[i], bfv[j], acc[i][j], 0, 0, 0);            \
                acc[i][j] = __builtin_amdgcn_mfma_f32_16x16x32_bf16(\
                    agv[i], bgv[j], acc[i][j], 0, 0, 0);            \
            }                                                       \
    }

    for (int kt = 0; kt < K / BK; ++kt) {
        const int k0 = kt * BK;
        gload_lds16(gA0 + k0, dA0);
        gload_lds16(gA1 + k0, dA1);
        gload_lds16(gA2 + k0, dA2);
        gload_lds16(gA3 + k0, dA3);
        gload_lds16(gB0 + k0, dB0);
        gload_lds16(gB1 + k0, dB1);
        gload_lds16(gB2 + k0, dB2);
        gload_lds16(gB3 + k0, dB3);
        __syncthreads();        // compiler drains vmcnt(0) -> tile valid
        COMPUTE();
        __syncthreads();        // all reads done before next overwrite
    }
#undef COMPUTE

    // ---- epilogue: 4 passes of 32 rows x 128 cols through ebuf ----
    // D layout: col = t, row = q*4 + reg  [m89/m91 verified]
#pragma unroll
    for (int p = 0; p < 4; ++p) {          // block rows [p*32, p*32+32)
        if (p) __syncthreads();
        if (wm == (p >> 1)) {
            int dt = p & 1;                // tm pair {2dt, 2dt+1}
#pragma unroll
            for (int half = 0; half < 2; ++half) {
                int tm = dt * 2 + half;
#pragma unroll
                for (int tn = 0; tn < 4; ++tn) {
                    int col = wn * 64 + tn * 16 + t;
#pragma unroll
                    for (int r = 0; r < 4; ++r) {
                        int brow = half * 16 + q * 4 + r;
                        ebuf[brow * ES + col] = acc[tm][tn][r];
                    }
                }
            }
        }
        __syncthreads();
#pragma unroll
        for (int rr = 0; rr < 4; ++rr) {
            int brow = rr * 8 + (tid >> 5);
            int col4 = tid & 31;
            float4 v = *(const float4*)(ebuf + brow * ES + col4 * 4);
            size_t grow = (size_t)(bm * 128 + p * 32 + brow);
            *(float4*)(C + grow * OUTD + bn * 128 + col4 * 4) = v;
        }
    }
}

extern "C" void kernel_launch(void* const* d_in, const int* in_sizes, int n_in,
                              void* d_out, int out_size, void* d_ws, size_t ws_size,
                              hipStream_t stream) {
    const float* x    = (const float*)d_in[0];
    const float* coef = (const float*)d_in[1];
    const float* w    = (const float*)d_in[2];
    float* out = (float*)d_out;

    unsigned short* xb   = (unsigned short*)d_ws;                                   // 16 MB
    unsigned short* weff = (unsigned short*)((char*)d_ws + (size_t)BATCH * IN * 2); // +2 MB

    prep_kernel<<<6144, 256, 0, stream>>>(x, coef, w, xb, weff);
    gemm_bt<<<dim3(BATCH / 128, OUTD / 128), 256, 0, stream>>>(xb, weff, out);
}

// Round 2
// 122.528 us; speedup vs baseline: 1.0330x; 1.0330x over previous
//
#include <hip/hip_runtime.h>
#include <hip/hip_bf16.h>
#include <stdint.h>

#define BATCH 8192
#define IN    1024
#define OUTD  1024
#define PBASIS 8

typedef __attribute__((ext_vector_type(8))) short bf16x8;
typedef __attribute__((ext_vector_type(4))) float floatx4;

__device__ __forceinline__ unsigned short f2bf(float f) {
    union { float f; unsigned u; } v; v.f = f;
    unsigned u = v.u;
    u += 0x7fffu + ((u >> 16) & 1u);   // RNE; inputs finite randn
    return (unsigned short)(u >> 16);
}

// Fused prep: blocks [0,4096) convert x -> bf16 (8 elem/thread);
// blocks [4096,6144) compute w_eff = bf16(sum_p coef * w) (2 elem/thread).
__global__ void prep_kernel(const float* __restrict__ x,
                            const float* __restrict__ coef,
                            const float* __restrict__ w,
                            unsigned short* __restrict__ xb,
                            unsigned short* __restrict__ weff) {
    int b = blockIdx.x;
    int tid = threadIdx.x;
    if (b < 4096) {
        int idx = b * 256 + tid;
        const float4* p = (const float4*)(x + (size_t)idx * 8);
        float4 a = p[0], c = p[1];
        uint4 o;
        o.x = (unsigned)f2bf(a.x) | ((unsigned)f2bf(a.y) << 16);
        o.y = (unsigned)f2bf(a.z) | ((unsigned)f2bf(a.w) << 16);
        o.z = (unsigned)f2bf(c.x) | ((unsigned)f2bf(c.y) << 16);
        o.w = (unsigned)f2bf(c.z) | ((unsigned)f2bf(c.w) << 16);
        ((uint4*)xb)[idx] = o;
    } else {
        int idx = (b - 4096) * 256 + tid;   // element pair index
        size_t e0 = (size_t)idx * 2;
        const float4* c4 = (const float4*)(coef + e0 * PBASIS);
        float4 a = c4[0], bb = c4[1], c = c4[2], d = c4[3];
        float s0 = (a.x + a.y + a.z + a.w) + (bb.x + bb.y + bb.z + bb.w);
        float s1 = (c.x + c.y + c.z + c.w) + (d.x + d.y + d.z + d.w);
        float2 ww = ((const float2*)w)[idx];
        unsigned b0 = f2bf(s0 * ww.x);
        unsigned b1 = f2bf(s1 * ww.y);
        ((unsigned*)weff)[idx] = b0 | (b1 << 16);
    }
}

__device__ __forceinline__ void gload_lds16(const void* g, void* l) {
    __builtin_amdgcn_global_load_lds(
        (const __attribute__((address_space(1))) unsigned int*)g,
        (__attribute__((address_space(3))) unsigned int*)l,
        16, 0, 0);
}

// Raw barrier + counted waits (T3+T4): loads stay in flight across barriers.
#define BARRIER()  asm volatile("s_barrier" ::: "memory")
#define WAIT_V6L0() asm volatile("s_waitcnt vmcnt(6) lgkmcnt(0)" ::: "memory")
#define WAIT_V0L0() asm volatile("s_waitcnt vmcnt(0) lgkmcnt(0)" ::: "memory")

// C[m,n] = sum_k A[m,k]*B[n,k]; A=[8192,1024], B=[1024,1024] bf16, C f32.
// BM=256 x BN=128 tile, BK=64, 512 threads = 8 waves (4M x 2N), per-wave
// 64x64 out (4x4 frags of 16x16x32). Tri-buffered LDS (3 x 48KB = 144KB,
// 1 block/CU), grid 32x8 = 256 blocks = 1/CU. Pipeline: during tile kt,
// issue tile kt+2's 6 global_load_lds into stage (kt+2)%3 (freed by kt-1,
// whose reads completed before kt's ready-barrier), then wait vmcnt(6)
// (tile kt+1 landed; kt+2's 6 stay in flight) + lgkmcnt(0) (no ds_read
// crosses the barrier) + raw s_barrier. Never drains vmcnt to 0 in the
// main loop. LDS contents/swizzle/fragment math identical to the verified
// 128x128 kernel (linear gload_lds dest + pre-swizzled source column;
// read chunk (kh*4+q)^(t&7)); accumulation order unchanged (kh=0 then 1
// per kt ascending) => bit-identical C, absmax 0.25.
__global__ __launch_bounds__(512, 2) void gemm_bt(
        const unsigned short* __restrict__ A,
        const unsigned short* __restrict__ B,
        float* __restrict__ C) {
    constexpr int K = IN, BK = 64, NT = K / BK;   // 16 K-steps
    constexpr int STG = 49152;                    // 48 KB per stage (A 32K + B 16K)
    constexpr int ES = 132;                       // epilogue row stride (floats)
    __shared__ __align__(16) char smem[3 * STG];  // 144 KiB
    float* ebuf = (float*)smem;                   // epilogue reuse (256*132*4 = 132K)

    const int tid  = threadIdx.x;
    const int bm   = blockIdx.x, bn = blockIdx.y;
    const int lane = tid & 63;
    const int wave = tid >> 6;     // 0..7
    const int wm   = wave >> 1;    // 0..3 along M
    const int wn   = wave & 1;     // 0..1 along N
    const int t    = lane & 15;    // M/N index within 16
    const int q    = lane >> 4;    // K-quad
    const int r8   = t & 7;        // XOR swizzle key

    // ---- staging map: 6 chunks/thread/K-step (A: j=0..3, B: j=0..1) ----
    // chunk g: row = g>>3, c = g&7; LDS slot = g (linear, required by
    // global_load_lds); global source column = c ^ (row&7) (involution).
    int g0 = tid,        ra0 = g0 >> 3, ca0 = (g0 & 7) ^ (ra0 & 7);
    int g1 = 512 + tid,  ra1 = g1 >> 3, ca1 = (g1 & 7) ^ (ra1 & 7);
    int g2 = 1024 + tid, ra2 = g2 >> 3, ca2 = (g2 & 7) ^ (ra2 & 7);
    int g3 = 1536 + tid, ra3 = g3 >> 3, ca3 = (g3 & 7) ^ (ra3 & 7);
    int h0 = tid,        rb0 = h0 >> 3, cb0 = (h0 & 7) ^ (rb0 & 7);
    int h1 = 512 + tid,  rb1 = h1 >> 3, cb1 = (h1 & 7) ^ (rb1 & 7);

    const unsigned short* gA0 = A + (size_t)(bm * 256 + ra0) * K + ca0 * 8;
    const unsigned short* gA1 = A + (size_t)(bm * 256 + ra1) * K + ca1 * 8;
    const unsigned short* gA2 = A + (size_t)(bm * 256 + ra2) * K + ca2 * 8;
    const unsigned short* gA3 = A + (size_t)(bm * 256 + ra3) * K + ca3 * 8;
    const unsigned short* gB0 = B + (size_t)(bn * 128 + rb0) * K + cb0 * 8;
    const unsigned short* gB1 = B + (size_t)(bn * 128 + rb1) * K + cb1 * 8;

    const int dA0 = g0 * 16, dA1 = g1 * 16, dA2 = g2 * 16, dA3 = g3 * 16;
    const int dB0 = 32768 + h0 * 16, dB1 = 32768 + h1 * 16;

    // ---- fragment byte offsets within a stage (A at 0, B at 32768) ----
    const int aO0 = ((wm * 64 + t) * 64 + ((0 + q) ^ r8) * 8) * 2;
    const int aO1 = ((wm * 64 + t) * 64 + ((4 + q) ^ r8) * 8) * 2;
    const int bO0 = 32768 + ((wn * 64 + t) * 64 + ((0 + q) ^ r8) * 8) * 2;
    const int bO1 = 32768 + ((wn * 64 + t) * 64 + ((4 + q) ^ r8) * 8) * 2;

    floatx4 acc[4][4];
#pragma unroll
    for (int i = 0; i < 4; ++i)
#pragma unroll
        for (int j = 0; j < 4; ++j)
            acc[i][j] = (floatx4){0.f, 0.f, 0.f, 0.f};

#define STAGE_A3(sp, ko)                                            \
    {                                                               \
        gload_lds16(gA0 + (ko), (sp) + dA0);                        \
        gload_lds16(gA1 + (ko), (sp) + dA1);                        \
        gload_lds16(gA2 + (ko), (sp) + dA2);                        \
    }
#define STAGE_B3(sp, ko)                                            \
    {                                                               \
        gload_lds16(gA3 + (ko), (sp) + dA3);                        \
        gload_lds16(gB0 + (ko), (sp) + dB0);                        \
        gload_lds16(gB1 + (ko), (sp) + dB1);                        \
    }
// One phase: 8 ds_read_b128 (4 A frags + 4 B frags, one k-slice) + 16 MFMA.
#define PHASE(sb, aO, bO)                                           \
    {                                                               \
        const char* ab = (sb) + (aO);                               \
        const char* bb = (sb) + (bO);                               \
        bf16x8 af0 = *(const bf16x8*)(ab + 0 * 2048);               \
        bf16x8 af1 = *(const bf16x8*)(ab + 1 * 2048);               \
        bf16x8 af2 = *(const bf16x8*)(ab + 2 * 2048);               \
        bf16x8 af3 = *(const bf16x8*)(ab + 3 * 2048);               \
        bf16x8 bf0 = *(const bf16x8*)(bb + 0 * 2048);               \
        bf16x8 bf1 = *(const bf16x8*)(bb + 1 * 2048);               \
        bf16x8 bf2 = *(const bf16x8*)(bb + 2 * 2048);               \
        bf16x8 bf3 = *(const bf16x8*)(bb + 3 * 2048);               \
        bf16x8 afv[4] = {af0, af1, af2, af3};                       \
        bf16x8 bfv[4] = {bf0, bf1, bf2, bf3};                       \
        __builtin_amdgcn_s_setprio(1);                              \
        _Pragma("unroll")                                           \
        for (int i = 0; i < 4; ++i)                                 \
            _Pragma("unroll")                                       \
            for (int j = 0; j < 4; ++j)                             \
                acc[i][j] = __builtin_amdgcn_mfma_f32_16x16x32_bf16(\
                    afv[i], bfv[j], acc[i][j], 0, 0, 0);            \
        __builtin_amdgcn_s_setprio(0);                              \
    }

    // ---- prologue: stage tiles 0 and 1, wait for tile 0 only ----
    {
        char* s0 = smem;
        char* s1 = smem + STG;
        STAGE_A3(s0, 0); STAGE_B3(s0, 0);
        STAGE_A3(s1, BK); STAGE_B3(s1, BK);
        WAIT_V6L0();       // tile 0 landed; tile 1's 6 loads in flight
        BARRIER();
    }

    int cur = 0;
    for (int kt = 0; kt < NT; ++kt) {
        char* sb = smem + cur * STG;
        int nx = cur + 2; if (nx >= 3) nx -= 3;
        char* sp = smem + nx * STG;
        const int kpre = (kt + 2) * BK;
        const bool pre = (kt < NT - 2);

        if (pre) STAGE_A3(sp, kpre);
        PHASE(sb, aO0, bO0);           // k-slice 0
        if (pre) STAGE_B3(sp, kpre);
        PHASE(sb, aO1, bO1);           // k-slice 1

        if (pre) { WAIT_V6L0(); }      // tile kt+1 ready; kt+2 in flight
        else     { WAIT_V0L0(); }      // tail: drain
        BARRIER();
        ++cur; if (cur == 3) cur = 0;
    }
#undef PHASE
#undef STAGE_A3
#undef STAGE_B3

    __syncthreads();   // full drain before LDS reuse as ebuf

    // ---- epilogue: dump 256x128 f32 via LDS (ES=132 pad), float4 out ----
    // D layout: col = t, row = q*4 + r  [m89/m91 verified]
#pragma unroll
    for (int tm = 0; tm < 4; ++tm)
#pragma unroll
        for (int tn = 0; tn < 4; ++tn)
#pragma unroll
            for (int r = 0; r < 4; ++r)
                ebuf[(wm * 64 + tm * 16 + q * 4 + r) * ES
                     + wn * 64 + tn * 16 + t] = acc[tm][tn][r];
    __syncthreads();
#pragma unroll
    for (int ps = 0; ps < 16; ++ps) {
        int row  = ps * 16 + (tid >> 5);
        int col4 = tid & 31;
        float4 v = *(const float4*)(ebuf + row * ES + col4 * 4);
        *(float4*)(C + (size_t)(bm * 256 + row) * OUTD + bn * 128 + col4 * 4) = v;
    }
}

extern "C" void kernel_launch(void* const* d_in, const int* in_sizes, int n_in,
                              void* d_out, int out_size, void* d_ws, size_t ws_size,
                              hipStream_t stream) {
    const float* x    = (const float*)d_in[0];
    const float* coef = (const float*)d_in[1];
    const float* w    = (const float*)d_in[2];
    float* out = (float*)d_out;

    unsigned short* xb   = (unsigned short*)d_ws;                                   // 16 MB
    unsigned short* weff = (unsigned short*)((char*)d_ws + (size_t)BATCH * IN * 2); // +2 MB

    prep_kernel<<<6144, 256, 0, stream>>>(x, coef, w, xb, weff);
    gemm_bt<<<dim3(BATCH / 256, OUTD / 128), 512, 0, stream>>>(xb, weff, out);
}